// Round 1
// baseline (482.763 us; speedup 1.0000x reference)
//
#include <hip/hip_runtime.h>

#define SDIM 10
#define HDIM 2048
#define LDIM 4096

// 1/sqrt(2048)
#define KSCALE 0.02209708691207961f

// ---------------------------------------------------------------------------
// Kernel A: k[b,s,o] = sum_h h_l[b,s,h]*w_k[o,h];  v[b,s,o] likewise with w_v.
// Wave layout: 8 o-values x 8 h-splits (each h-split covers 256 h).
// block 256 = 4 waves (32 o per block). grid (2048/32, B).
// ---------------------------------------------------------------------------
__global__ __launch_bounds__(256) void kv_kernel(
    const float* __restrict__ h_l, const float* __restrict__ w_k,
    const float* __restrict__ w_v, float* __restrict__ k_out,
    float* __restrict__ v_out) {
  const int b = blockIdx.y;
  const int wave = threadIdx.x >> 6;
  const int lane = threadIdx.x & 63;
  const int o_sub = lane & 7;
  const int hsplit = lane >> 3;
  const int o = blockIdx.x * 32 + wave * 8 + o_sub;

  const float4* hl4 = (const float4*)(h_l + (size_t)b * SDIM * HDIM) + hsplit * 64;
  const float4* wk4 = (const float4*)(w_k + (size_t)o * HDIM) + hsplit * 64;
  const float4* wv4 = (const float4*)(w_v + (size_t)o * HDIM) + hsplit * 64;

  float acck[SDIM], accv[SDIM];
#pragma unroll
  for (int s = 0; s < SDIM; s++) { acck[s] = 0.f; accv[s] = 0.f; }

  for (int i = 0; i < 64; i++) {
    float4 wk = wk4[i];
    float4 wv = wv4[i];
#pragma unroll
    for (int s = 0; s < SDIM; s++) {
      float4 hv = hl4[(size_t)s * 512 + i];
      acck[s] += wk.x * hv.x + wk.y * hv.y + wk.z * hv.z + wk.w * hv.w;
      accv[s] += wv.x * hv.x + wv.y * hv.y + wv.z * hv.z + wv.w * hv.w;
    }
  }
  // reduce across the 8 h-splits (lane bits 3,4,5)
#pragma unroll
  for (int s = 0; s < SDIM; s++) {
    acck[s] += __shfl_xor(acck[s], 8);
    acck[s] += __shfl_xor(acck[s], 16);
    acck[s] += __shfl_xor(acck[s], 32);
    accv[s] += __shfl_xor(accv[s], 8);
    accv[s] += __shfl_xor(accv[s], 16);
    accv[s] += __shfl_xor(accv[s], 32);
  }
  if (hsplit == 0) {
#pragma unroll
    for (int s = 0; s < SDIM; s++) {
      k_out[((size_t)b * SDIM + s) * HDIM + o] = acck[s];
      v_out[((size_t)b * SDIM + s) * HDIM + o] = accv[s];
    }
  }
}

// ---------------------------------------------------------------------------
// Kernel B1: kk[b,s,h] = sum_o k[b,s,o] * w_q[o,h]   (coalesced over h)
// Wave layout: 16 h x 4 o-splits (each o-split covers 512 o).
// block 256 = 4 waves (64 h per block). grid (2048/64, B).
// ---------------------------------------------------------------------------
__global__ __launch_bounds__(256) void kk_kernel(
    const float* __restrict__ k_in, const float* __restrict__ w_q,
    float* __restrict__ kk_out) {
  const int b = blockIdx.y;
  const int wave = threadIdx.x >> 6;
  const int lane = threadIdx.x & 63;
  const int h_sub = lane & 15;
  const int osplit = lane >> 4;
  const int h = blockIdx.x * 64 + wave * 16 + h_sub;
  const float* kb = k_in + (size_t)b * SDIM * HDIM;

  float acc[SDIM];
#pragma unroll
  for (int s = 0; s < SDIM; s++) acc[s] = 0.f;

  const int o0 = osplit * 512;
  for (int o4 = 0; o4 < 128; o4++) {
    const int o = o0 + o4 * 4;
    float w0 = w_q[(size_t)(o + 0) * HDIM + h];
    float w1 = w_q[(size_t)(o + 1) * HDIM + h];
    float w2 = w_q[(size_t)(o + 2) * HDIM + h];
    float w3 = w_q[(size_t)(o + 3) * HDIM + h];
#pragma unroll
    for (int s = 0; s < SDIM; s++) {
      const float4 kv = *(const float4*)(kb + (size_t)s * HDIM + o);
      acc[s] += kv.x * w0 + kv.y * w1 + kv.z * w2 + kv.w * w3;
    }
  }
#pragma unroll
  for (int s = 0; s < SDIM; s++) {
    acc[s] += __shfl_xor(acc[s], 16);
    acc[s] += __shfl_xor(acc[s], 32);
  }
  if (osplit == 0) {
#pragma unroll
    for (int s = 0; s < SDIM; s++)
      kk_out[((size_t)b * SDIM + s) * HDIM + h] = acc[s];
  }
}

// ---------------------------------------------------------------------------
// Kernel B2: vo[b,s,o] = sum_h v[b,s,h] * w_o[o,h]   (same shape as kernel A)
// ---------------------------------------------------------------------------
__global__ __launch_bounds__(256) void vo_kernel(
    const float* __restrict__ v_in, const float* __restrict__ w_o,
    float* __restrict__ vo_out) {
  const int b = blockIdx.y;
  const int wave = threadIdx.x >> 6;
  const int lane = threadIdx.x & 63;
  const int o_sub = lane & 7;
  const int hsplit = lane >> 3;
  const int o = blockIdx.x * 32 + wave * 8 + o_sub;

  const float4* vb4 = (const float4*)(v_in + (size_t)b * SDIM * HDIM) + hsplit * 64;
  const float4* wo4 = (const float4*)(w_o + (size_t)o * HDIM) + hsplit * 64;

  float acc[SDIM];
#pragma unroll
  for (int s = 0; s < SDIM; s++) acc[s] = 0.f;

  for (int i = 0; i < 64; i++) {
    float4 wv = wo4[i];
#pragma unroll
    for (int s = 0; s < SDIM; s++) {
      float4 hv = vb4[(size_t)s * 512 + i];
      acc[s] += wv.x * hv.x + wv.y * hv.y + wv.z * hv.z + wv.w * hv.w;
    }
  }
#pragma unroll
  for (int s = 0; s < SDIM; s++) {
    acc[s] += __shfl_xor(acc[s], 8);
    acc[s] += __shfl_xor(acc[s], 16);
    acc[s] += __shfl_xor(acc[s], 32);
  }
  if (hsplit == 0) {
#pragma unroll
    for (int s = 0; s < SDIM; s++)
      vo_out[((size_t)b * SDIM + s) * HDIM + o] = acc[s];
  }
}

// ---------------------------------------------------------------------------
// Kernel C (main, memory-bound): per row l of h_english:
//   scores[s] = dot(h_e[b,l,:], kk[b,s,:]) / sqrt(H)
//   p = softmax(scores)
//   out[b,l,h] = h_e[b,l,h] + alpha * sum_s p[s]*vo[b,s,h]
// One wave handles 4 rows (register-blocked to cut kk/vo L2 traffic 4x).
// block 256 = 4 waves = 16 rows. grid (4096/16, B).
// ---------------------------------------------------------------------------
__global__ __launch_bounds__(256, 2) void attn_kernel(
    const float* __restrict__ h_e, const float* __restrict__ kk,
    const float* __restrict__ vo, const float* __restrict__ alpha_p,
    float* __restrict__ out) {
  const int b = blockIdx.y;
  const int wave = threadIdx.x >> 6;
  const int lane = threadIdx.x & 63;
  const int row0 = blockIdx.x * 16 + wave * 4;
  const float alpha = *alpha_p;
  const float* kkb = kk + (size_t)b * SDIM * HDIM;
  const float* vob = vo + (size_t)b * SDIM * HDIM;
  const size_t rowbase = ((size_t)b * LDIM + row0) * HDIM;

  // load 4 rows of h_english into registers (lane covers 32 h as 8 float4s)
  float4 he[4][8];
#pragma unroll
  for (int r = 0; r < 4; r++) {
    const float4* src = (const float4*)(h_e + rowbase + (size_t)r * HDIM);
#pragma unroll
    for (int i = 0; i < 8; i++) he[r][i] = src[i * 64 + lane];
  }

  float acc[4][SDIM];
#pragma unroll
  for (int r = 0; r < 4; r++)
#pragma unroll
    for (int s = 0; s < SDIM; s++) acc[r][s] = 0.f;

  // scores: each kk float4 loaded once, reused for 4 rows
#pragma unroll
  for (int i = 0; i < 8; i++) {
#pragma unroll
    for (int s = 0; s < SDIM; s++) {
      float4 kv = ((const float4*)(kkb + (size_t)s * HDIM))[i * 64 + lane];
#pragma unroll
      for (int r = 0; r < 4; r++)
        acc[r][s] += he[r][i].x * kv.x + he[r][i].y * kv.y +
                     he[r][i].z * kv.z + he[r][i].w * kv.w;
    }
  }

  // cross-lane butterfly reduce, then scale by 1/sqrt(H)
#pragma unroll
  for (int r = 0; r < 4; r++)
#pragma unroll
    for (int s = 0; s < SDIM; s++) {
      float v = acc[r][s];
      v += __shfl_xor(v, 1);
      v += __shfl_xor(v, 2);
      v += __shfl_xor(v, 4);
      v += __shfl_xor(v, 8);
      v += __shfl_xor(v, 16);
      v += __shfl_xor(v, 32);
      acc[r][s] = v * KSCALE;
    }

  // softmax over S=10 (every lane redundantly), fold alpha into probs
#pragma unroll
  for (int r = 0; r < 4; r++) {
    float m = acc[r][0];
#pragma unroll
    for (int s = 1; s < SDIM; s++) m = fmaxf(m, acc[r][s]);
    float sum = 0.f;
#pragma unroll
    for (int s = 0; s < SDIM; s++) {
      acc[r][s] = __expf(acc[r][s] - m);
      sum += acc[r][s];
    }
    const float inv = alpha / sum;
#pragma unroll
    for (int s = 0; s < SDIM; s++) acc[r][s] *= inv;
  }

  // output: out = h_e + sum_s (alpha*p[s]) * vo[s]; vo float4 reused for 4 rows
#pragma unroll
  for (int i = 0; i < 8; i++) {
    float4 o4[4];
#pragma unroll
    for (int r = 0; r < 4; r++) o4[r] = he[r][i];
#pragma unroll
    for (int s = 0; s < SDIM; s++) {
      float4 vv = ((const float4*)(vob + (size_t)s * HDIM))[i * 64 + lane];
#pragma unroll
      for (int r = 0; r < 4; r++) {
        o4[r].x += acc[r][s] * vv.x;
        o4[r].y += acc[r][s] * vv.y;
        o4[r].z += acc[r][s] * vv.z;
        o4[r].w += acc[r][s] * vv.w;
      }
    }
#pragma unroll
    for (int r = 0; r < 4; r++)
      ((float4*)(out + rowbase + (size_t)r * HDIM))[i * 64 + lane] = o4[r];
  }
}

// ---------------------------------------------------------------------------
extern "C" void kernel_launch(void* const* d_in, const int* in_sizes, int n_in,
                              void* d_out, int out_size, void* d_ws, size_t ws_size,
                              hipStream_t stream) {
  const float* h_e   = (const float*)d_in[0];  // [4,4096,2048]
  const float* h_l   = (const float*)d_in[1];  // [4,10,2048]
  const float* w_q   = (const float*)d_in[2];  // [2048,2048]
  const float* w_k   = (const float*)d_in[3];
  const float* w_v   = (const float*)d_in[4];
  const float* w_o   = (const float*)d_in[5];
  const float* alpha = (const float*)d_in[6];  // scalar
  float* out = (float*)d_out;

  float* ws    = (float*)d_ws;
  float* k_ws  = ws;            // 4*10*2048
  float* v_ws  = ws + 81920;
  float* kk_ws = ws + 163840;
  float* vo_ws = ws + 245760;   // total 327680 floats = 1.31 MB

  kv_kernel<<<dim3(64, 4), 256, 0, stream>>>(h_l, w_k, w_v, k_ws, v_ws);
  kk_kernel<<<dim3(32, 4), 256, 0, stream>>>(k_ws, w_q, kk_ws);
  vo_kernel<<<dim3(64, 4), 256, 0, stream>>>(v_ws, w_o, vo_ws);
  attn_kernel<<<dim3(256, 4), 256, 0, stream>>>(h_e, kk_ws, vo_ws, alpha, out);
}

// Round 2
// 412.138 us; speedup vs baseline: 1.1714x; 1.1714x over previous
//
#include <hip/hip_runtime.h>

#define SDIM 10
#define HDIM 2048
#define LDIM 4096
#define BDIM 4

// 1/sqrt(2048)
#define KSCALE 0.02209708691207961f

// ---------------------------------------------------------------------------
// Kernel 1: k[b,s,o] = sum_h h_l[b,s,h]*w_k[o,h];  v likewise with w_v.
// One wave per (o-pair, b). Wave reads w rows coalesced (lane i -> float4 i),
// butterfly-reduces 20 dots (10 s x 2 o) per matrix.
// grid (256, 4) x block 256 (4 waves) -> 1024 waves/batch covering o in pairs.
// ---------------------------------------------------------------------------
__global__ __launch_bounds__(256) void kv_kernel(
    const float* __restrict__ h_l, const float* __restrict__ w_k,
    const float* __restrict__ w_v, float* __restrict__ k_out,
    float* __restrict__ v_out) {
  const int b = blockIdx.y;
  const int wave = threadIdx.x >> 6;
  const int lane = threadIdx.x & 63;
  const int opair = blockIdx.x * 4 + wave;
  const int o0 = opair * 2;

  const float4* hl4 = (const float4*)(h_l + (size_t)b * SDIM * HDIM);
  const float4* wk0 = (const float4*)(w_k + (size_t)o0 * HDIM);
  const float4* wk1 = (const float4*)(w_k + (size_t)(o0 + 1) * HDIM);
  const float4* wv0 = (const float4*)(w_v + (size_t)o0 * HDIM);
  const float4* wv1 = (const float4*)(w_v + (size_t)(o0 + 1) * HDIM);

  float ak0[SDIM], ak1[SDIM], av0[SDIM], av1[SDIM];
#pragma unroll
  for (int s = 0; s < SDIM; s++) { ak0[s] = ak1[s] = av0[s] = av1[s] = 0.f; }

#pragma unroll
  for (int j = 0; j < 8; j++) {
    const int idx = j * 64 + lane;
    const float4 a0 = wk0[idx], a1 = wk1[idx];
    const float4 c0 = wv0[idx], c1 = wv1[idx];
#pragma unroll
    for (int s = 0; s < SDIM; s++) {
      const float4 h = hl4[s * 512 + idx];
      ak0[s] += a0.x * h.x + a0.y * h.y + a0.z * h.z + a0.w * h.w;
      ak1[s] += a1.x * h.x + a1.y * h.y + a1.z * h.z + a1.w * h.w;
      av0[s] += c0.x * h.x + c0.y * h.y + c0.z * h.z + c0.w * h.w;
      av1[s] += c1.x * h.x + c1.y * h.y + c1.z * h.z + c1.w * h.w;
    }
  }
#pragma unroll
  for (int s = 0; s < SDIM; s++) {
#pragma unroll
    for (int d = 1; d < 64; d <<= 1) {
      ak0[s] += __shfl_xor(ak0[s], d);
      ak1[s] += __shfl_xor(ak1[s], d);
      av0[s] += __shfl_xor(av0[s], d);
      av1[s] += __shfl_xor(av1[s], d);
    }
  }
  if (lane == 0) {
#pragma unroll
    for (int s = 0; s < SDIM; s++) {
      const size_t base = ((size_t)b * SDIM + s) * HDIM + o0;
      k_out[base]     = ak0[s];
      k_out[base + 1] = ak1[s];
      v_out[base]     = av0[s];
      v_out[base + 1] = av1[s];
    }
  }
}

// ---------------------------------------------------------------------------
// Kernel 2a: kk partials. kk[b,s,h] = sum_o k[b,s,o]*w_q[o,h].
// Output-stationary: thread -> float4 of h (w_q reads fully coalesced),
// k scalars broadcast from LDS. o split into 16 chunks of 128, s into halves
// of 5 -> grid (2 htile, 32 oc*shalf, 4 b) = 256 blocks. Partials to ws.
// ---------------------------------------------------------------------------
#define OSPLIT 16
__global__ __launch_bounds__(256) void kk_part_kernel(
    const float* __restrict__ k_in, const float* __restrict__ w_q,
    float* __restrict__ part) {
  const int b = blockIdx.z;
  const int oc = blockIdx.y >> 1;
  const int s0 = (blockIdx.y & 1) * 5;
  const int f4 = blockIdx.x * 256 + threadIdx.x;  // float4 index in [0,512)

  __shared__ float ksh[5 * 128];
  for (int idx = threadIdx.x; idx < 5 * 128; idx += 256) {
    const int s = idx >> 7, oo = idx & 127;
    ksh[idx] = k_in[((size_t)b * SDIM + s0 + s) * HDIM + oc * 128 + oo];
  }
  __syncthreads();

  float4 acc[5];
#pragma unroll
  for (int s = 0; s < 5; s++) acc[s] = make_float4(0.f, 0.f, 0.f, 0.f);

  const float4* wq4 = (const float4*)w_q;
  for (int oo = 0; oo < 128; oo++) {
    const float4 w = wq4[(size_t)(oc * 128 + oo) * 512 + f4];
#pragma unroll
    for (int s = 0; s < 5; s++) {
      const float kv = ksh[s * 128 + oo];
      acc[s].x += kv * w.x; acc[s].y += kv * w.y;
      acc[s].z += kv * w.z; acc[s].w += kv * w.w;
    }
  }
#pragma unroll
  for (int s = 0; s < 5; s++) {
    ((float4*)part)[(((size_t)oc * BDIM + b) * SDIM + s0 + s) * 512 + f4] = acc[s];
  }
}

// Kernel 2b: reduce 16 partials -> kk. 20480 float4 outputs.
__global__ __launch_bounds__(256) void kk_reduce_kernel(
    const float* __restrict__ part, float* __restrict__ kk_out) {
  const int t = blockIdx.x * 256 + threadIdx.x;  // [0, 20480)
  const float4* p4 = (const float4*)part;
  float4 acc = make_float4(0.f, 0.f, 0.f, 0.f);
#pragma unroll
  for (int p = 0; p < OSPLIT; p++) {
    const float4 v = p4[(size_t)p * 20480 + t];
    acc.x += v.x; acc.y += v.y; acc.z += v.z; acc.w += v.w;
  }
  ((float4*)kk_out)[t] = acc;
}

// ---------------------------------------------------------------------------
// Kernel 3: vo[b,s,o] = sum_h v[b,s,h]*w_o[o,h]. Same wave-per-(o-pair,b)
// structure as kernel 1, single matrix.
// ---------------------------------------------------------------------------
__global__ __launch_bounds__(256) void vo_kernel(
    const float* __restrict__ v_in, const float* __restrict__ w_o,
    float* __restrict__ vo_out) {
  const int b = blockIdx.y;
  const int wave = threadIdx.x >> 6;
  const int lane = threadIdx.x & 63;
  const int opair = blockIdx.x * 4 + wave;
  const int o0 = opair * 2;

  const float4* vb4 = (const float4*)(v_in + (size_t)b * SDIM * HDIM);
  const float4* wo0 = (const float4*)(w_o + (size_t)o0 * HDIM);
  const float4* wo1 = (const float4*)(w_o + (size_t)(o0 + 1) * HDIM);

  float a0[SDIM], a1[SDIM];
#pragma unroll
  for (int s = 0; s < SDIM; s++) { a0[s] = a1[s] = 0.f; }

#pragma unroll
  for (int j = 0; j < 8; j++) {
    const int idx = j * 64 + lane;
    const float4 w0 = wo0[idx], w1 = wo1[idx];
#pragma unroll
    for (int s = 0; s < SDIM; s++) {
      const float4 h = vb4[s * 512 + idx];
      a0[s] += w0.x * h.x + w0.y * h.y + w0.z * h.z + w0.w * h.w;
      a1[s] += w1.x * h.x + w1.y * h.y + w1.z * h.z + w1.w * h.w;
    }
  }
#pragma unroll
  for (int s = 0; s < SDIM; s++) {
#pragma unroll
    for (int d = 1; d < 64; d <<= 1) {
      a0[s] += __shfl_xor(a0[s], d);
      a1[s] += __shfl_xor(a1[s], d);
    }
  }
  if (lane == 0) {
#pragma unroll
    for (int s = 0; s < SDIM; s++) {
      const size_t base = ((size_t)b * SDIM + s) * HDIM + o0;
      vo_out[base]     = a0[s];
      vo_out[base + 1] = a1[s];
    }
  }
}

// ---------------------------------------------------------------------------
// Kernel 4 (main): per row l: scores = h_e . kk / sqrt(H); p = softmax;
// out = h_e + alpha * sum_s p_s * vo_s.  2 rows per wave, block 256 (8 rows),
// grid (512, 4) = 2048 blocks -> 32 waves/CU launched.
// ---------------------------------------------------------------------------
__global__ __launch_bounds__(256) void attn_kernel(
    const float* __restrict__ h_e, const float* __restrict__ kk,
    const float* __restrict__ vo, const float* __restrict__ alpha_p,
    float* __restrict__ out) {
  const int b = blockIdx.y;
  const int wave = threadIdx.x >> 6;
  const int lane = threadIdx.x & 63;
  const int row0 = blockIdx.x * 8 + wave * 2;
  const float alpha = *alpha_p;
  const float4* kkb = (const float4*)(kk + (size_t)b * SDIM * HDIM);
  const float4* vob = (const float4*)(vo + (size_t)b * SDIM * HDIM);
  const size_t rowbase = ((size_t)b * LDIM + row0) * HDIM;

  float4 he[2][8];
#pragma unroll
  for (int r = 0; r < 2; r++) {
    const float4* src = (const float4*)(h_e + rowbase + (size_t)r * HDIM);
#pragma unroll
    for (int i = 0; i < 8; i++) he[r][i] = src[i * 64 + lane];
  }

  float acc[2][SDIM];
#pragma unroll
  for (int r = 0; r < 2; r++)
#pragma unroll
    for (int s = 0; s < SDIM; s++) acc[r][s] = 0.f;

#pragma unroll
  for (int i = 0; i < 8; i++) {
#pragma unroll
    for (int s = 0; s < SDIM; s++) {
      const float4 kv = kkb[s * 512 + i * 64 + lane];
#pragma unroll
      for (int r = 0; r < 2; r++)
        acc[r][s] += he[r][i].x * kv.x + he[r][i].y * kv.y +
                     he[r][i].z * kv.z + he[r][i].w * kv.w;
    }
  }

#pragma unroll
  for (int r = 0; r < 2; r++)
#pragma unroll
    for (int s = 0; s < SDIM; s++) {
      float v = acc[r][s];
      v += __shfl_xor(v, 1);
      v += __shfl_xor(v, 2);
      v += __shfl_xor(v, 4);
      v += __shfl_xor(v, 8);
      v += __shfl_xor(v, 16);
      v += __shfl_xor(v, 32);
      acc[r][s] = v * KSCALE;
    }

#pragma unroll
  for (int r = 0; r < 2; r++) {
    float m = acc[r][0];
#pragma unroll
    for (int s = 1; s < SDIM; s++) m = fmaxf(m, acc[r][s]);
    float sum = 0.f;
#pragma unroll
    for (int s = 0; s < SDIM; s++) {
      acc[r][s] = __expf(acc[r][s] - m);
      sum += acc[r][s];
    }
    const float inv = alpha / sum;
#pragma unroll
    for (int s = 0; s < SDIM; s++) acc[r][s] *= inv;
  }

#pragma unroll
  for (int i = 0; i < 8; i++) {
    float4 o4[2];
#pragma unroll
    for (int r = 0; r < 2; r++) o4[r] = he[r][i];
#pragma unroll
    for (int s = 0; s < SDIM; s++) {
      const float4 vv = vob[s * 512 + i * 64 + lane];
#pragma unroll
      for (int r = 0; r < 2; r++) {
        o4[r].x += acc[r][s] * vv.x;
        o4[r].y += acc[r][s] * vv.y;
        o4[r].z += acc[r][s] * vv.z;
        o4[r].w += acc[r][s] * vv.w;
      }
    }
#pragma unroll
    for (int r = 0; r < 2; r++)
      ((float4*)(out + rowbase + (size_t)r * HDIM))[i * 64 + lane] = o4[r];
  }
}

// ---------------------------------------------------------------------------
extern "C" void kernel_launch(void* const* d_in, const int* in_sizes, int n_in,
                              void* d_out, int out_size, void* d_ws, size_t ws_size,
                              hipStream_t stream) {
  const float* h_e   = (const float*)d_in[0];  // [4,4096,2048]
  const float* h_l   = (const float*)d_in[1];  // [4,10,2048]
  const float* w_q   = (const float*)d_in[2];  // [2048,2048]
  const float* w_k   = (const float*)d_in[3];
  const float* w_v   = (const float*)d_in[4];
  const float* w_o   = (const float*)d_in[5];
  const float* alpha = (const float*)d_in[6];  // scalar
  float* out = (float*)d_out;

  float* ws      = (float*)d_ws;
  float* k_ws    = ws;             // 81920 floats
  float* v_ws    = ws + 81920;
  float* kk_ws   = ws + 163840;
  float* vo_ws   = ws + 245760;
  float* part_ws = ws + 327680;    // 16*4*10*2048 = 1310720 floats (5.2 MB)

  kv_kernel<<<dim3(256, BDIM), 256, 0, stream>>>(h_l, w_k, w_v, k_ws, v_ws);
  kk_part_kernel<<<dim3(2, 32, BDIM), 256, 0, stream>>>(k_ws, w_q, part_ws);
  vo_kernel<<<dim3(256, BDIM), 256, 0, stream>>>(v_ws, w_o, vo_ws);
  kk_reduce_kernel<<<80, 256, 0, stream>>>(part_ws, kk_ws);
  attn_kernel<<<dim3(512, BDIM), 256, 0, stream>>>(h_e, kk_ws, vo_ws, alpha, out);
}